// Round 2
// 433.730 us; speedup vs baseline: 1.1371x; 1.1371x over previous
//
#include <hip/hip_runtime.h>
#include <math.h>

#define NB 10
#define PPC 29          // 3*NB-1
#define CCH 4
#define HID 64
#define HH 256
#define WW 256
#define BB 16
#define TB 1.0f
#define MINW 0.001f
#define MINH 0.001f
#define MIND 0.001f

#define ZTOT (BB*CCH*HH*WW)     // 4194304

// Tile: 16 wide x 8 tall. M=128 pixels, N=128 (116 valid), K=576.
#define TH 8
#define TWD 16
#define HALO_PIX 180            // 10 rows x 18 cols
#define HSTR 72                 // s_hid row stride (bf16): 64 + 8 pad -> rows 16B-aligned (b128 reads)
#define PSTR 117                // p_buf row stride (f32): odd -> conflict-free spline reads
#define NCOLS 116               // valid N columns; >=116 is zero-padding (never stored)
#define W2B_ELEMS (18*8*64*8)   // 73728 bf16 per copy; hi+lo = 294912 B in d_ws (NO extra space used)

typedef __attribute__((ext_vector_type(8))) short short8v;
typedef __attribute__((ext_vector_type(4))) short short4v;
typedef __attribute__((ext_vector_type(4))) float f32x4;

__device__ inline unsigned short f2bf(float f) {
    unsigned u = __float_as_uint(f);
    unsigned r = (u + 0x7FFFu + ((u >> 16) & 1u)) >> 16;
    return (unsigned short)r;
}
__device__ inline float bf2f(unsigned short s) {
    return __uint_as_float(((unsigned)s) << 16);
}

__global__ void zero_lad_kernel(float* out) {
    out[ZTOT + threadIdx.x] = 0.0f;
}

// Prepack W2 -> bf16 fragment order, hi/lo split for ~fp32 effective precision.
// w2b[copy(2)][kidx(18)][ntile(8)][lane(64)][j(8)]
// kidx = tap*2 + ks; n = ntile*16 + (lane&15); ci = ks*32 + (lane>>4)*8 + j
//
// W1 stuffing: W2 columns n>=116 are zero padding whose MFMA products land in
// discarded output cols (epilogue stores only col<116). We stash the conv1
// weight fragments there, so total workspace stays exactly 294912 B:
//   W1 fragment f = ks*4 + nt1 (ks in 0..1, nt1 in 0..3), read-lane L, elem j:
//     co = nt1*16 + (L&15); k = ks*32 + (L>>4)*8 + j; v = (k<36) ? W1[co][k&3][k>>2] : 0
//   stored at (kidx = f*2 + (L>>5), nt = 7, slotLane, j) with
//     m = L&31, slotLane = (m>>3)*16 + 4 + (m&7)   (i.e. lane&15 in [4,12))
__global__ void prepack_w2(const float* __restrict__ W2, const float* __restrict__ W1,
                           unsigned short* __restrict__ w2b) {
    int idx = blockIdx.x * 256 + threadIdx.x;
    if (idx >= W2B_ELEMS) return;
    int j    = idx & 7;
    int lane = (idx >> 3) & 63;
    int nt   = (idx >> 9) & 7;
    int kidx = idx >> 12;            // 0..17
    int tap  = kidx >> 1;
    int ks   = kidx & 1;
    int ky   = tap / 3;
    int kx   = tap - ky * 3;
    int n    = nt * 16 + (lane & 15);
    int ci   = ks * 32 + (lane >> 4) * 8 + j;
    float v = 0.0f;
    if (n < PPC * CCH) v = W2[((n * HID + ci) * 3 + ky) * 3 + kx];

    // ---- W1 slot? (padding region) ----
    int l15s = lane & 15;
    if (nt == 7 && kidx < 16 && l15s >= 4 && l15s < 12) {
        int f   = kidx >> 1;
        int hi5 = kidx & 1;
        int L   = hi5 * 32 + (lane >> 4) * 8 + (l15s - 4);
        int ks2 = f >> 2;
        int nt1 = f & 3;
        int co  = nt1 * 16 + (L & 15);
        int k   = ks2 * 32 + (L >> 4) * 8 + j;
        v = 0.0f;
        if (k < 36) {
            int tp  = k >> 2;
            int c   = k & 3;
            int ky2 = tp / 3;
            int kx2 = tp - ky2 * 3;
            v = W1[((co * CCH + c) * 3 + ky2) * 3 + kx2];
        }
    }

    unsigned short hi = f2bf(v);
    float rem = v - bf2f(hi);
    w2b[idx]             = hi;
    w2b[idx + W2B_ELEMS] = f2bf(rem);
}

__global__ __launch_bounds__(256, 3)
void fused_kernel(const float* __restrict__ x, const float* __restrict__ clean,
                  const float* __restrict__ b1,
                  const float* __restrict__ b2, const unsigned short* __restrict__ w2b,
                  float* __restrict__ out)
{
    // s_un: phase B/C = s_hid (180*HSTR bf16 = 25920 B); epilogue = p_buf (64*117 f32 = 29952 B).
    // Aliasing is barrier-ordered: all MFMA reads of s_hid complete before first p_buf store.
    __shared__ __align__(16) float s_un[64 * PSTR];        // 29952 B
    __shared__ __align__(16) unsigned short s_cl[2 * 960]; // clean hi+lo, [cy(12)][cx(20)][c(4)], 3840 B
    __shared__ float s_red[4];

    unsigned short* s_hid = (unsigned short*)s_un;

    const int tid  = threadIdx.x;
    const int blk  = blockIdx.x;
    const int b    = blk >> 9;
    const int ty   = (blk >> 4) & 31;
    const int tx   = blk & 15;
    const int Y0 = ty * TH, X0 = tx * TWD;

    const int w    = tid >> 6;        // wave id == spline channel c
    const int lane = tid & 63;
    const int l15  = lane & 15;
    const int quad = lane >> 4;
    const int wy   = w & 1;           // M half: mtiles wy*4 .. wy*4+3 (pixel rows)
    const int wx   = w >> 1;          // N half: ntiles wx*4 .. wx*4+3

    // ---------- Phase A: stage clean tile (12 x 20 x 4ch, zero-padded) as bf16 hi/lo ----------
    for (int i = tid; i < 960; i += 256) {
        int c  = i / 240;             // plane-major iteration -> coalesced global loads
        int r  = i - c * 240;
        int cy = r / 20;
        int cx = r - cy * 20;
        int iy = Y0 - 2 + cy, ix = X0 - 2 + cx;
        float v = 0.0f;
        if (iy >= 0 && iy < HH && ix >= 0 && ix < WW)
            v = clean[((b*CCH + c) << 16) + iy*WW + ix];
        unsigned short hi = f2bf(v);
        int o = r * 4 + c;            // c-contiguous LDS layout for b64 fragment reads
        s_cl[o]       = hi;
        s_cl[960 + o] = f2bf(v - bf2f(hi));
    }
    __syncthreads();

    // ---------- Phase B: hid = relu(conv1(clean)) via MFMA (implicit GEMM) ----------
    // M = 180 halo pixels (pad 192 -> 12 mtiles, 3/wave), N = 64 (4 ntiles), K = 36 pad 64.
    // Precision: A,B both hi/lo bf16; A_hi*B_hi + A_hi*B_lo + A_lo*B_hi ~= fp32 conv1.
    {
        const short8v* __restrict__ wv = (const short8v*)w2b;
        const int hi5 = lane >> 5;
        const int mm  = lane & 31;
        const int slotLane = ((mm >> 3) << 4) + 4 + (mm & 7);   // inverse of prepack's L decode

        f32x4 acc1[3][4];
        #pragma unroll
        for (int nt = 0; nt < 4; ++nt) {
            float bv = b1[nt*16 + l15];               // C col = l15 -> co
            #pragma unroll
            for (int mt = 0; mt < 3; ++mt) {
                acc1[mt][nt][0] = bv; acc1[mt][nt][1] = bv;
                acc1[mt][nt][2] = bv; acc1[mt][nt][3] = bv;
            }
        }
        // Per-lane tap offsets: quad q covers taps {2q,2q+1} (ks=0) and tap 8 (ks=1; k>=36 zeroed in B).
        int t0 = quad * 2, t1 = quad * 2 + 1;
        int ky0 = t0 / 3, kx0 = t0 - ky0 * 3;
        int ky1 = t1 / 3, kx1 = t1 - ky1 * 3;
        const int o0 = (ky0 * 20 + kx0) * 4;
        const int o1 = (ky1 * 20 + kx1) * 4;
        const int o8 = (2 * 20 + 2) * 4;              // tap 8 -> (ky,kx)=(2,2)

        #pragma unroll
        for (int ks = 0; ks < 2; ++ks) {
            short8v bh[4], bl[4];
            #pragma unroll
            for (int nt = 0; nt < 4; ++nt) {
                int i8 = (((ks*4 + nt)*2 + hi5)*8 + 7)*64 + slotLane;  // (kidx, nt=7, slotLane)
                bh[nt] = wv[i8];
                bl[nt] = wv[i8 + 9216];               // + W2B_ELEMS/8 -> lo copy
            }
            const int oA = ks ? o8 : o0;
            const int oB = ks ? o8 : o1;
            #pragma unroll
            for (int mt = 0; mt < 3; ++mt) {
                int p  = (w*3 + mt)*16 + l15;          // A row = halo pixel
                int pc = p > HALO_PIX-1 ? HALO_PIX-1 : p;   // clamp pad rows (results discarded)
                int hy = pc / 18, hx = pc - hy * 18;
                int base = (hy * 20 + hx) * 4;
                short4v h0 = *(const short4v*)(s_cl + base + oA);
                short4v h1 = *(const short4v*)(s_cl + base + oB);
                short4v g0 = *(const short4v*)(s_cl + 960 + base + oA);
                short4v g1 = *(const short4v*)(s_cl + 960 + base + oB);
                short8v ah = __builtin_shufflevector(h0, h1, 0,1,2,3,4,5,6,7);
                short8v al = __builtin_shufflevector(g0, g1, 0,1,2,3,4,5,6,7);
                #pragma unroll
                for (int nt = 0; nt < 4; ++nt) {
                    acc1[mt][nt] = __builtin_amdgcn_mfma_f32_16x16x32_bf16(ah, bh[nt], acc1[mt][nt], 0,0,0);
                    acc1[mt][nt] = __builtin_amdgcn_mfma_f32_16x16x32_bf16(ah, bl[nt], acc1[mt][nt], 0,0,0);
                    acc1[mt][nt] = __builtin_amdgcn_mfma_f32_16x16x32_bf16(al, bh[nt], acc1[mt][nt], 0,0,0);
                }
            }
        }
        // Write s_hid bf16. Out-of-image halo pixels must be ZERO (conv2 SAME padding), not relu(b1).
        #pragma unroll
        for (int mt = 0; mt < 3; ++mt) {
            #pragma unroll
            for (int r = 0; r < 4; ++r) {
                int p = (w*3 + mt)*16 + quad*4 + r;    // C row = quad*4 + reg
                if (p < HALO_PIX) {
                    int hy = p / 18, hx = p - hy * 18;
                    int iy = Y0 - 1 + hy, ix = X0 - 1 + hx;
                    bool valid = (iy >= 0 && iy < HH && ix >= 0 && ix < WW);
                    #pragma unroll
                    for (int nt = 0; nt < 4; ++nt) {
                        float v = valid ? fmaxf(acc1[mt][nt][r], 0.0f) : 0.0f;
                        s_hid[p*HSTR + nt*16 + l15] = f2bf(v);
                    }
                }
            }
        }
    }
    __syncthreads();

    // ---------- Phase C: conv2 as implicit GEMM via MFMA (B = W2_hi + W2_lo) ----------
    // Wave (wy,wx): 4 mtiles x 4 ntiles = 16 acc tiles (64 f32/thread).
    f32x4 acc[4][4];
    #pragma unroll
    for (int mi = 0; mi < 4; ++mi)
        #pragma unroll
        for (int t = 0; t < 4; ++t) {
            acc[mi][t][0] = 0.f; acc[mi][t][1] = 0.f;
            acc[mi][t][2] = 0.f; acc[mi][t][3] = 0.f;
        }

    const short8v* __restrict__ wbv_hi = (const short8v*)w2b;
    const short8v* __restrict__ wbv_lo = (const short8v*)(w2b + W2B_ELEMS);
    // A addr (shorts): ((wy*4+mi+ky)*18 + l15+kx)*HSTR + quad*8 + ks*32  (16B-aligned -> b128)
    const int abase = (wy*4) * (18*HSTR) + l15*HSTR + quad*8;

    for (int tap = 0; tap < 9; ++tap) {
        int ky = tap / 3;
        int kx = tap - ky * 3;
        int roff = abase + ky*(18*HSTR) + kx*HSTR;
        #pragma unroll
        for (int ks = 0; ks < 2; ++ks) {
            int boff = ((tap*2 + ks)*8 + wx*4)*64 + lane;
            short8v afr[4];
            #pragma unroll
            for (int mi = 0; mi < 4; ++mi)
                afr[mi] = *(const short8v*)(s_hid + roff + mi*(18*HSTR) + ks*32);
            short8v bfr[4];
            #pragma unroll
            for (int t = 0; t < 4; ++t)
                bfr[t] = wbv_hi[boff + t*64];
            #pragma unroll
            for (int mi = 0; mi < 4; ++mi)
                #pragma unroll
                for (int t = 0; t < 4; ++t)
                    acc[mi][t] = __builtin_amdgcn_mfma_f32_16x16x32_bf16(
                        afr[mi], bfr[t], acc[mi][t], 0, 0, 0);
            #pragma unroll
            for (int t = 0; t < 4; ++t)
                bfr[t] = wbv_lo[boff + t*64];
            #pragma unroll
            for (int mi = 0; mi < 4; ++mi)
                #pragma unroll
                for (int t = 0; t < 4; ++t)
                    acc[mi][t] = __builtin_amdgcn_mfma_f32_16x16x32_bf16(
                        afr[mi], bfr[t], acc[mi][t], 0, 0, 0);
        }
    }

    // ---------- Epilogue: 2 chunks of 64 pixels through LDS p_buf (aliases s_hid), then spline ----------
    float* p_buf = s_un;
    const float* b2c = b2 + w * PPC;      // wave-uniform -> scalar loads
    float lad = 0.0f;

    for (int chunk = 0; chunk < 2; ++chunk) {
        __syncthreads();   // chunk 0: all s_hid MFMA reads done; chunk 1: chunk-0 spline reads done
        if (wy == chunk) {
            #pragma unroll
            for (int mi = 0; mi < 4; ++mi) {
                #pragma unroll
                for (int t = 0; t < 4; ++t) {
                    int col = (wx*4 + t)*16 + l15;
                    if (col < NCOLS) {    // cols >=116 are padding; would wrap PSTR (R3 bug)
                        f32x4 v = acc[mi][t];
                        int base = (mi*16 + quad*4) * PSTR + col;
                        p_buf[base]          = v[0];
                        p_buf[base + PSTR]   = v[1];
                        p_buf[base + 2*PSTR] = v[2];
                        p_buf[base + 3*PSTR] = v[3];
                    }
                }
            }
        }
        __syncthreads();

        // spline: thread -> (c = w, chunk-local pixel = lane)
        float pv[PPC];
        #pragma unroll
        for (int j = 0; j < PPC; ++j)
            pv[j] = p_buf[lane * PSTR + w * PPC + j];

        const float scale = 0.125f;   // 1/sqrt(HIDDEN)
        float uw[NB], uh[NB], ud9[NB-1];
        #pragma unroll
        for (int j = 0; j < NB; ++j)   uw[j]  = (pv[j]      + b2c[j])      * scale;
        #pragma unroll
        for (int j = 0; j < NB; ++j)   uh[j]  = (pv[NB+j]   + b2c[NB+j])   * scale;
        #pragma unroll
        for (int j = 0; j < NB-1; ++j) ud9[j] =  pv[2*NB+j] + b2c[2*NB+j];

        float mw = uw[0];
        #pragma unroll
        for (int j = 1; j < NB; ++j) mw = fmaxf(mw, uw[j]);
        float sw = 0.0f;
        #pragma unroll
        for (int j = 0; j < NB; ++j) { uw[j] = __expf(uw[j] - mw); sw += uw[j]; }
        float isw = 1.0f / sw;
        float cw[NB+1];
        cw[0] = -TB;
        float run = 0.0f;
        #pragma unroll
        for (int j = 0; j < NB; ++j) {
            float wj = MINW + (1.0f - MINW*NB) * (uw[j] * isw);
            run += wj;
            cw[j+1] = -TB + 2.0f*TB*run;
        }
        cw[NB] = TB;

        float mh = uh[0];
        #pragma unroll
        for (int j = 1; j < NB; ++j) mh = fmaxf(mh, uh[j]);
        float sh = 0.0f;
        #pragma unroll
        for (int j = 0; j < NB; ++j) { uh[j] = __expf(uh[j] - mh); sh += uh[j]; }
        float ish = 1.0f / sh;
        float chh[NB+1];
        chh[0] = -TB;
        float runh = 0.0f;
        #pragma unroll
        for (int j = 0; j < NB; ++j) {
            float hj = MINH + (1.0f - MINH*NB) * (uh[j] * ish);
            runh += hj;
            chh[j+1] = -TB + 2.0f*TB*runh;
        }
        chh[NB] = TB;

        float dv[NB+1];
        dv[0] = 1.0f; dv[NB] = 1.0f;
        #pragma unroll
        for (int k = 0; k < NB-1; ++k) {
            float v = ud9[k];
            // softplus(v) = max(v,0) + log(1+exp(-|v|)); fast intrinsics are safe:
            // exp(-|v|) tiny -> 1+t rounds to 1 -> log 0, matching log1p asymptote
            float sp = fmaxf(v, 0.0f) + __logf(1.0f + __expf(-fabsf(v)));
            dv[k+1] = MIND + sp;
        }

        int iy = Y0 + chunk*4 + quad;
        int ix = X0 + l15;
        int gidx = ((b*CCH + w) << 16) + iy*WW + ix;
        float xv  = x[gidx];
        float xin = fminf(fmaxf(xv, -TB), TB);
        int cnt = 0;
        #pragma unroll
        for (int k = 0; k <= NB; ++k) cnt += (xin >= cw[k]) ? 1 : 0;
        int idx = cnt - 1;
        idx = idx < 0 ? 0 : (idx > NB-1 ? NB-1 : idx);

        float icw = cw[0], inw = cw[1], ich = chh[0], inh = chh[1], d0 = dv[0], d1 = dv[1];
        #pragma unroll
        for (int k = 1; k < NB; ++k) {
            bool m = (idx == k);
            icw = m ? cw[k]    : icw;
            inw = m ? cw[k+1]  : inw;
            ich = m ? chh[k]   : ich;
            inh = m ? chh[k+1] : inh;
            d0  = m ? dv[k]    : d0;
            d1  = m ? dv[k+1]  : d1;
        }
        float ibw = inw - icw;
        float ihh = inh - ich;
        float idl = ihh / ibw;
        float th  = (xin - icw) / ibw;
        float omt = 1.0f - th;
        float tt  = th * omt;
        float numer = ihh * (idl*th*th + d0*tt);
        float den   = idl + (d0 + d1 - 2.0f*idl)*tt;
        float z_in  = ich + numer/den;
        float dnum  = idl*idl*(d1*th*th + 2.0f*idl*tt + d0*omt*omt);
        float lad_in = __logf(dnum) - 2.0f*__logf(den);
        bool inside = (xv >= -TB) && (xv <= TB);
        float z = inside ? z_in : xv;
        if (inside) lad += lad_in;
        out[gidx] = z;
    }

    // ---------- block-reduce lad, one atomic per block ----------
    #pragma unroll
    for (int off = 32; off >= 1; off >>= 1)
        lad += __shfl_xor(lad, off, 64);
    if (lane == 0) s_red[w] = lad;
    __syncthreads();
    if (tid == 0)
        atomicAdd(out + ZTOT + b, s_red[0] + s_red[1] + s_red[2] + s_red[3]);
}

extern "C" void kernel_launch(void* const* d_in, const int* in_sizes, int n_in,
                              void* d_out, int out_size, void* d_ws, size_t ws_size,
                              hipStream_t stream) {
    const float* x     = (const float*)d_in[0];
    const float* clean = (const float*)d_in[1];
    const float* W1    = (const float*)d_in[2];
    const float* b1    = (const float*)d_in[3];
    const float* W2    = (const float*)d_in[4];
    const float* b2    = (const float*)d_in[5];
    float* out = (float*)d_out;
    unsigned short* w2b = (unsigned short*)d_ws;   // exactly 294912 B (W2 hi+lo, W1 stuffed in padding)

    zero_lad_kernel<<<1, 16, 0, stream>>>(out);
    prepack_w2<<<(W2B_ELEMS + 255)/256, 256, 0, stream>>>(W2, W1, w2b);
    fused_kernel<<<BB*32*16, 256, 0, stream>>>(x, clean, b1, b2, w2b, out);
}

// Round 3
// 380.607 us; speedup vs baseline: 1.2958x; 1.1396x over previous
//
#include <hip/hip_runtime.h>
#include <math.h>

#define NB 10
#define PPC 29          // 3*NB-1
#define CCH 4
#define HID 64
#define HH 256
#define WW 256
#define BB 16
#define TB 1.0f
#define MINW 0.001f
#define MINH 0.001f
#define MIND 0.001f

#define ZTOT (BB*CCH*HH*WW)     // 4194304

// Tile: 16 wide x 8 tall. M=128 pixels, N=128 (116 valid), K=576.
#define TH 8
#define TWD 16
#define HALO_PIX 180            // 10 rows x 18 cols
#define HSTR 72                 // s_hid row stride (bf16): 64 + 8 pad -> rows 16B-aligned (b128 reads)
#define PSTR 117                // p_buf row stride (f32): odd -> conflict-free spline reads
#define NCOLS 116               // valid N columns; >=116 is zero-padding (never stored)
#define W2B_ELEMS (18*8*64*8)   // 73728 bf16 per copy; hi+lo = 294912 B in d_ws (NO extra space used)

typedef __attribute__((ext_vector_type(8))) short short8v;
typedef __attribute__((ext_vector_type(4))) short short4v;
typedef __attribute__((ext_vector_type(4))) float f32x4;

__device__ inline unsigned short f2bf(float f) {
    unsigned u = __float_as_uint(f);
    unsigned r = (u + 0x7FFFu + ((u >> 16) & 1u)) >> 16;
    return (unsigned short)r;
}
__device__ inline float bf2f(unsigned short s) {
    return __uint_as_float(((unsigned)s) << 16);
}

__global__ void zero_lad_kernel(float* out) {
    out[ZTOT + threadIdx.x] = 0.0f;
}

// Prepack W2 -> bf16 fragment order, hi/lo split for ~fp32 effective precision.
// w2b[copy(2)][kidx(18)][ntile(8)][lane(64)][j(8)]
// kidx = tap*2 + ks; n = ntile*16 + (lane&15); ci = ks*32 + (lane>>4)*8 + j
//
// W1 stuffing: W2 columns n>=116 are zero padding whose MFMA products land in
// discarded output cols (epilogue stores only col<116). We stash the conv1
// weight fragments there, so total workspace stays exactly 294912 B:
//   W1 fragment f = ks*4 + nt1 (ks in 0..1, nt1 in 0..3), read-lane L, elem j:
//     co = nt1*16 + (L&15); k = ks*32 + (L>>4)*8 + j; v = (k<36) ? W1[co][k&3][k>>2] : 0
//   stored at (kidx = f*2 + (L>>5), nt = 7, slotLane, j) with
//     m = L&31, slotLane = (m>>3)*16 + 4 + (m&7)   (i.e. lane&15 in [4,12))
__global__ void prepack_w2(const float* __restrict__ W2, const float* __restrict__ W1,
                           unsigned short* __restrict__ w2b) {
    int idx = blockIdx.x * 256 + threadIdx.x;
    if (idx >= W2B_ELEMS) return;
    int j    = idx & 7;
    int lane = (idx >> 3) & 63;
    int nt   = (idx >> 9) & 7;
    int kidx = idx >> 12;            // 0..17
    int tap  = kidx >> 1;
    int ks   = kidx & 1;
    int ky   = tap / 3;
    int kx   = tap - ky * 3;
    int n    = nt * 16 + (lane & 15);
    int ci   = ks * 32 + (lane >> 4) * 8 + j;
    float v = 0.0f;
    if (n < PPC * CCH) v = W2[((n * HID + ci) * 3 + ky) * 3 + kx];

    // ---- W1 slot? (padding region) ----
    int l15s = lane & 15;
    if (nt == 7 && kidx < 16 && l15s >= 4 && l15s < 12) {
        int f   = kidx >> 1;
        int hi5 = kidx & 1;
        int L   = hi5 * 32 + (lane >> 4) * 8 + (l15s - 4);
        int ks2 = f >> 2;
        int nt1 = f & 3;
        int co  = nt1 * 16 + (L & 15);
        int k   = ks2 * 32 + (L >> 4) * 8 + j;
        v = 0.0f;
        if (k < 36) {
            int tp  = k >> 2;
            int c   = k & 3;
            int ky2 = tp / 3;
            int kx2 = tp - ky2 * 3;
            v = W1[((co * CCH + c) * 3 + ky2) * 3 + kx2];
        }
    }

    unsigned short hi = f2bf(v);
    float rem = v - bf2f(hi);
    w2b[idx]             = hi;
    w2b[idx + W2B_ELEMS] = f2bf(rem);
}

__global__ __launch_bounds__(256, 3)
void fused_kernel(const float* __restrict__ x, const float* __restrict__ clean,
                  const float* __restrict__ b1,
                  const float* __restrict__ b2, const unsigned short* __restrict__ w2b,
                  float* __restrict__ out)
{
    // s_un: phase B/C = s_hid (180*HSTR bf16 = 25920 B); epilogue = p_buf (64*117 f32 = 29952 B).
    // Aliasing is barrier-ordered: all MFMA reads of s_hid complete before first p_buf store.
    __shared__ __align__(16) float s_un[64 * PSTR];        // 29952 B
    __shared__ __align__(16) unsigned short s_cl[2 * 960]; // clean hi+lo, [cy(12)][cx(20)][c(4)], 3840 B
    __shared__ float s_red[4];

    unsigned short* s_hid = (unsigned short*)s_un;

    const int tid  = threadIdx.x;
    const int blk  = blockIdx.x;
    const int b    = blk >> 9;
    const int ty   = (blk >> 4) & 31;
    const int tx   = blk & 15;
    const int Y0 = ty * TH, X0 = tx * TWD;

    const int w    = tid >> 6;        // wave id == spline channel c
    const int lane = tid & 63;
    const int l15  = lane & 15;
    const int quad = lane >> 4;
    const int wy   = w & 1;           // M half: mtiles wy*4 .. wy*4+3 (pixel rows)
    const int wx   = w >> 1;          // N half: ntiles wx*4 .. wx*4+3

    // ---------- Phase A: stage clean tile (12 x 20 x 4ch, zero-padded) as bf16 hi/lo ----------
    for (int i = tid; i < 960; i += 256) {
        int c  = i / 240;             // plane-major iteration -> coalesced global loads
        int r  = i - c * 240;
        int cy = r / 20;
        int cx = r - cy * 20;
        int iy = Y0 - 2 + cy, ix = X0 - 2 + cx;
        float v = 0.0f;
        if (iy >= 0 && iy < HH && ix >= 0 && ix < WW)
            v = clean[((b*CCH + c) << 16) + iy*WW + ix];
        unsigned short hi = f2bf(v);
        int o = r * 4 + c;            // c-contiguous LDS layout for b64 fragment reads
        s_cl[o]       = hi;
        s_cl[960 + o] = f2bf(v - bf2f(hi));
    }
    __syncthreads();

    // ---------- Phase B: hid = relu(conv1(clean)) via MFMA (implicit GEMM) ----------
    // M = 180 halo pixels (pad 192 -> 12 mtiles, 3/wave), N = 64 (4 ntiles), K = 36 pad 64.
    // Precision: A,B both hi/lo bf16; A_hi*B_hi + A_hi*B_lo + A_lo*B_hi ~= fp32 conv1.
    // Register diet (R3): ah/al hoisted per ks (24 regs), bh/bl loaded one pair
    // at a time (8 regs) -> no 32-reg fragment block live across the MFMA loop.
    {
        const short8v* __restrict__ wv = (const short8v*)w2b;
        const int hi5 = lane >> 5;
        const int mm  = lane & 31;
        const int slotLane = ((mm >> 3) << 4) + 4 + (mm & 7);   // inverse of prepack's L decode

        f32x4 acc1[3][4];
        #pragma unroll
        for (int nt = 0; nt < 4; ++nt) {
            float bv = b1[nt*16 + l15];               // C col = l15 -> co
            #pragma unroll
            for (int mt = 0; mt < 3; ++mt) {
                acc1[mt][nt][0] = bv; acc1[mt][nt][1] = bv;
                acc1[mt][nt][2] = bv; acc1[mt][nt][3] = bv;
            }
        }
        // Per-lane tap offsets: quad q covers taps {2q,2q+1} (ks=0) and tap 8 (ks=1; k>=36 zeroed in B).
        int t0 = quad * 2, t1 = quad * 2 + 1;
        int ky0 = t0 / 3, kx0 = t0 - ky0 * 3;
        int ky1 = t1 / 3, kx1 = t1 - ky1 * 3;
        const int o0 = (ky0 * 20 + kx0) * 4;
        const int o1 = (ky1 * 20 + kx1) * 4;
        const int o8 = (2 * 20 + 2) * 4;              // tap 8 -> (ky,kx)=(2,2)

        #pragma unroll
        for (int ks = 0; ks < 2; ++ks) {
            const int oA = ks ? o8 : o0;
            const int oB = ks ? o8 : o1;
            short8v ah[3], al[3];
            #pragma unroll
            for (int mt = 0; mt < 3; ++mt) {
                int p  = (w*3 + mt)*16 + l15;          // A row = halo pixel
                int pc = p > HALO_PIX-1 ? HALO_PIX-1 : p;   // clamp pad rows (results discarded)
                int hy = pc / 18, hx = pc - hy * 18;
                int base = (hy * 20 + hx) * 4;
                short4v h0 = *(const short4v*)(s_cl + base + oA);
                short4v h1 = *(const short4v*)(s_cl + base + oB);
                short4v g0 = *(const short4v*)(s_cl + 960 + base + oA);
                short4v g1 = *(const short4v*)(s_cl + 960 + base + oB);
                ah[mt] = __builtin_shufflevector(h0, h1, 0,1,2,3,4,5,6,7);
                al[mt] = __builtin_shufflevector(g0, g1, 0,1,2,3,4,5,6,7);
            }
            #pragma unroll
            for (int nt = 0; nt < 4; ++nt) {
                int i8 = (((ks*4 + nt)*2 + hi5)*8 + 7)*64 + slotLane;  // (kidx, nt=7, slotLane)
                short8v bh = wv[i8];
                short8v bl = wv[i8 + 9216];            // + W2B_ELEMS/8 -> lo copy
                #pragma unroll
                for (int mt = 0; mt < 3; ++mt) {
                    acc1[mt][nt] = __builtin_amdgcn_mfma_f32_16x16x32_bf16(ah[mt], bh, acc1[mt][nt], 0,0,0);
                    acc1[mt][nt] = __builtin_amdgcn_mfma_f32_16x16x32_bf16(ah[mt], bl, acc1[mt][nt], 0,0,0);
                    acc1[mt][nt] = __builtin_amdgcn_mfma_f32_16x16x32_bf16(al[mt], bh, acc1[mt][nt], 0,0,0);
                }
            }
        }
        // Write s_hid bf16. Out-of-image halo pixels must be ZERO (conv2 SAME padding), not relu(b1).
        #pragma unroll
        for (int mt = 0; mt < 3; ++mt) {
            #pragma unroll
            for (int r = 0; r < 4; ++r) {
                int p = (w*3 + mt)*16 + quad*4 + r;    // C row = quad*4 + reg
                if (p < HALO_PIX) {
                    int hy = p / 18, hx = p - hy * 18;
                    int iy = Y0 - 1 + hy, ix = X0 - 1 + hx;
                    bool valid = (iy >= 0 && iy < HH && ix >= 0 && ix < WW);
                    #pragma unroll
                    for (int nt = 0; nt < 4; ++nt) {
                        float v = valid ? fmaxf(acc1[mt][nt][r], 0.0f) : 0.0f;
                        s_hid[p*HSTR + nt*16 + l15] = f2bf(v);
                    }
                }
            }
        }
    }
    __syncthreads();

    // ---------- Phase C: conv2 as implicit GEMM via MFMA (B = W2_hi + W2_lo) ----------
    // Wave (wy,wx): 4 mtiles x 4 ntiles = 16 acc tiles (64 f32/thread).
    f32x4 acc[4][4];
    #pragma unroll
    for (int mi = 0; mi < 4; ++mi)
        #pragma unroll
        for (int t = 0; t < 4; ++t) {
            acc[mi][t][0] = 0.f; acc[mi][t][1] = 0.f;
            acc[mi][t][2] = 0.f; acc[mi][t][3] = 0.f;
        }

    const short8v* __restrict__ wbv_hi = (const short8v*)w2b;
    const short8v* __restrict__ wbv_lo = (const short8v*)(w2b + W2B_ELEMS);
    // A addr (shorts): ((wy*4+mi+ky)*18 + l15+kx)*HSTR + quad*8 + ks*32  (16B-aligned -> b128)
    const int abase = (wy*4) * (18*HSTR) + l15*HSTR + quad*8;

    for (int tap = 0; tap < 9; ++tap) {
        int ky = tap / 3;
        int kx = tap - ky * 3;
        int roff = abase + ky*(18*HSTR) + kx*HSTR;
        #pragma unroll
        for (int ks = 0; ks < 2; ++ks) {
            int boff = ((tap*2 + ks)*8 + wx*4)*64 + lane;
            short8v afr[4];
            #pragma unroll
            for (int mi = 0; mi < 4; ++mi)
                afr[mi] = *(const short8v*)(s_hid + roff + mi*(18*HSTR) + ks*32);
            short8v bfr[4];
            #pragma unroll
            for (int t = 0; t < 4; ++t)
                bfr[t] = wbv_hi[boff + t*64];
            #pragma unroll
            for (int mi = 0; mi < 4; ++mi)
                #pragma unroll
                for (int t = 0; t < 4; ++t)
                    acc[mi][t] = __builtin_amdgcn_mfma_f32_16x16x32_bf16(
                        afr[mi], bfr[t], acc[mi][t], 0, 0, 0);
            #pragma unroll
            for (int t = 0; t < 4; ++t)
                bfr[t] = wbv_lo[boff + t*64];
            #pragma unroll
            for (int mi = 0; mi < 4; ++mi)
                #pragma unroll
                for (int t = 0; t < 4; ++t)
                    acc[mi][t] = __builtin_amdgcn_mfma_f32_16x16x32_bf16(
                        afr[mi], bfr[t], acc[mi][t], 0, 0, 0);
        }
    }

    // ---------- Epilogue: 2 chunks of 64 pixels through LDS p_buf (aliases s_hid), then spline ----------
    // Register diet (R3): no pv[]/chh[]/dv[] arrays; heights selected during the
    // cumsum; only the 2 needed derivatives get softplus (runtime-indexed LDS/b2 reads).
    float* p_buf = s_un;
    const float* b2c = b2 + w * PPC;      // wave-uniform -> scalar loads
    float lad = 0.0f;

    for (int chunk = 0; chunk < 2; ++chunk) {
        __syncthreads();   // chunk 0: all s_hid MFMA reads done; chunk 1: chunk-0 spline reads done
        if (wy == chunk) {
            #pragma unroll
            for (int mi = 0; mi < 4; ++mi) {
                #pragma unroll
                for (int t = 0; t < 4; ++t) {
                    int col = (wx*4 + t)*16 + l15;
                    if (col < NCOLS) {    // cols >=116 are padding; would wrap PSTR (R3 bug)
                        f32x4 v = acc[mi][t];
                        int base = (mi*16 + quad*4) * PSTR + col;
                        p_buf[base]          = v[0];
                        p_buf[base + PSTR]   = v[1];
                        p_buf[base + 2*PSTR] = v[2];
                        p_buf[base + 3*PSTR] = v[3];
                    }
                }
            }
        }
        __syncthreads();

        // spline: thread -> (c = w, chunk-local pixel = lane)
        int iy = Y0 + chunk*4 + quad;
        int ix = X0 + l15;
        int gidx = ((b*CCH + w) << 16) + iy*WW + ix;
        float xv  = x[gidx];              // issued early; bin search needs it
        float xin = fminf(fmaxf(xv, -TB), TB);

        const int pbase = lane * PSTR + w * PPC;
        const float scale = 0.125f;   // 1/sqrt(HIDDEN)

        // ---- widths softmax -> cw[] ----
        float uw[NB];
        #pragma unroll
        for (int j = 0; j < NB; ++j) uw[j] = (p_buf[pbase + j] + b2c[j]) * scale;
        float mw = uw[0];
        #pragma unroll
        for (int j = 1; j < NB; ++j) mw = fmaxf(mw, uw[j]);
        float sw = 0.0f;
        #pragma unroll
        for (int j = 0; j < NB; ++j) { uw[j] = __expf(uw[j] - mw); sw += uw[j]; }
        float isw = 1.0f / sw;
        float cw[NB+1];
        cw[0] = -TB;
        float run = 0.0f;
        #pragma unroll
        for (int j = 0; j < NB; ++j) {
            float wj = MINW + (1.0f - MINW*NB) * (uw[j] * isw);
            run += wj;
            cw[j+1] = -TB + 2.0f*TB*run;
        }
        cw[NB] = TB;

        // ---- bin search ----
        int cnt = 0;
        #pragma unroll
        for (int k = 0; k <= NB; ++k) cnt += (xin >= cw[k]) ? 1 : 0;
        int idx = cnt - 1;
        idx = idx < 0 ? 0 : (idx > NB-1 ? NB-1 : idx);

        float icw = cw[0], inw = cw[1];
        #pragma unroll
        for (int k = 1; k < NB; ++k) {
            bool m = (idx == k);
            icw = m ? cw[k]   : icw;
            inw = m ? cw[k+1] : inw;
        }

        // ---- heights softmax, ich/inh selected during cumsum (no chh[] array) ----
        float uh[NB];
        #pragma unroll
        for (int j = 0; j < NB; ++j) uh[j] = (p_buf[pbase + NB + j] + b2c[NB + j]) * scale;
        float mh = uh[0];
        #pragma unroll
        for (int j = 1; j < NB; ++j) mh = fmaxf(mh, uh[j]);
        float sh = 0.0f;
        #pragma unroll
        for (int j = 0; j < NB; ++j) { uh[j] = __expf(uh[j] - mh); sh += uh[j]; }
        float ish = 1.0f / sh;
        float ich = -TB, inh = -TB;
        float runh = 0.0f;
        #pragma unroll
        for (int j = 0; j < NB; ++j) {
            float c0 = -TB + 2.0f*TB*runh;            // chh[j]
            float hj = MINH + (1.0f - MINH*NB) * (uh[j] * ish);
            runh += hj;
            float c1 = (j == NB-1) ? TB : (-TB + 2.0f*TB*runh);  // chh[j+1]
            bool m = (idx == j);
            ich = m ? c0 : ich;
            inh = m ? c1 : inh;
        }

        // ---- derivatives: only d0 = dv[idx], d1 = dv[idx+1] (2 softplus, not 9) ----
        // dv[0] = dv[NB] = 1.0 (linear tails); dv[k+1] = MIND + softplus(ud9[k])
        int k0c = idx - 1; k0c = k0c < 0 ? 0 : k0c;
        int k1c = idx > NB-2 ? NB-2 : idx;
        float u0 = p_buf[pbase + 2*NB + k0c] + b2c[2*NB + k0c];
        float u1 = p_buf[pbase + 2*NB + k1c] + b2c[2*NB + k1c];
        float sp0 = fmaxf(u0, 0.0f) + __logf(1.0f + __expf(-fabsf(u0)));
        float sp1 = fmaxf(u1, 0.0f) + __logf(1.0f + __expf(-fabsf(u1)));
        float d0 = (idx == 0)    ? 1.0f : (MIND + sp0);
        float d1 = (idx == NB-1) ? 1.0f : (MIND + sp1);

        float ibw = inw - icw;
        float ihh = inh - ich;
        float idl = ihh / ibw;
        float th  = (xin - icw) / ibw;
        float omt = 1.0f - th;
        float tt  = th * omt;
        float numer = ihh * (idl*th*th + d0*tt);
        float den   = idl + (d0 + d1 - 2.0f*idl)*tt;
        float z_in  = ich + numer/den;
        float dnum  = idl*idl*(d1*th*th + 2.0f*idl*tt + d0*omt*omt);
        float lad_in = __logf(dnum) - 2.0f*__logf(den);
        bool inside = (xv >= -TB) && (xv <= TB);
        float z = inside ? z_in : xv;
        if (inside) lad += lad_in;
        out[gidx] = z;
    }

    // ---------- block-reduce lad, one atomic per block ----------
    #pragma unroll
    for (int off = 32; off >= 1; off >>= 1)
        lad += __shfl_xor(lad, off, 64);
    if (lane == 0) s_red[w] = lad;
    __syncthreads();
    if (tid == 0)
        atomicAdd(out + ZTOT + b, s_red[0] + s_red[1] + s_red[2] + s_red[3]);
}

extern "C" void kernel_launch(void* const* d_in, const int* in_sizes, int n_in,
                              void* d_out, int out_size, void* d_ws, size_t ws_size,
                              hipStream_t stream) {
    const float* x     = (const float*)d_in[0];
    const float* clean = (const float*)d_in[1];
    const float* W1    = (const float*)d_in[2];
    const float* b1    = (const float*)d_in[3];
    const float* W2    = (const float*)d_in[4];
    const float* b2    = (const float*)d_in[5];
    float* out = (float*)d_out;
    unsigned short* w2b = (unsigned short*)d_ws;   // exactly 294912 B (W2 hi+lo, W1 stuffed in padding)

    zero_lad_kernel<<<1, 16, 0, stream>>>(out);
    prepack_w2<<<(W2B_ELEMS + 255)/256, 256, 0, stream>>>(W2, W1, w2b);
    fused_kernel<<<BB*32*16, 256, 0, stream>>>(x, clean, b1, b2, w2b, out);
}

// Round 4
// 366.316 us; speedup vs baseline: 1.3464x; 1.0390x over previous
//
#include <hip/hip_runtime.h>
#include <math.h>

#define NB 10
#define PPC 29          // 3*NB-1
#define CCH 4
#define HID 64
#define HH 256
#define WW 256
#define BB 16
#define TB 1.0f
#define MINW 0.001f
#define MINH 0.001f
#define MIND 0.001f

#define ZTOT (BB*CCH*HH*WW)     // 4194304

// Tile: 16 wide x 8 tall. M=128 pixels, N=128 (116 valid), K=576.
#define TH 8
#define TWD 16
#define HALO_PIX 180            // 10 rows x 18 cols
#define HSTR 72                 // s_hid row stride (bf16): 64 + 8 pad -> rows 16B-aligned (b128 reads)
#define PSTR 117                // p_buf row stride (f32): odd -> conflict-free spline reads
#define NCOLS 116               // valid N columns; >=116 is zero-padding (never stored)
#define W2B_ELEMS (18*8*64*8)   // 73728 bf16 per copy; hi+lo = 294912 B in d_ws (NO extra space used)

typedef __attribute__((ext_vector_type(8))) short short8v;
typedef __attribute__((ext_vector_type(4))) short short4v;
typedef __attribute__((ext_vector_type(4))) float f32x4;

__device__ inline unsigned short f2bf(float f) {
    unsigned u = __float_as_uint(f);
    unsigned r = (u + 0x7FFFu + ((u >> 16) & 1u)) >> 16;
    return (unsigned short)r;
}
__device__ inline float bf2f(unsigned short s) {
    return __uint_as_float(((unsigned)s) << 16);
}

__global__ void zero_lad_kernel(float* out) {
    out[ZTOT + threadIdx.x] = 0.0f;
}

// Prepack W2 -> bf16 fragment order, hi/lo split for ~fp32 effective precision.
// w2b[copy(2)][kidx(18)][ntile(8)][lane(64)][j(8)]
// kidx = tap*2 + ks; n = ntile*16 + (lane&15); ci = ks*32 + (lane>>4)*8 + j
//
// W1 stuffing: W2 columns n>=116 are zero padding whose MFMA products land in
// discarded output cols (epilogue stores only col<116). We stash the conv1
// weight fragments there, so total workspace stays exactly 294912 B:
//   W1 fragment f = ks*4 + nt1 (ks in 0..1, nt1 in 0..3), read-lane L, elem j:
//     co = nt1*16 + (L&15); k = ks*32 + (L>>4)*8 + j; v = (k<36) ? W1[co][k&3][k>>2] : 0
//   stored at (kidx = f*2 + (L>>5), nt = 7, slotLane, j) with
//     m = L&31, slotLane = (m>>3)*16 + 4 + (m&7)   (i.e. lane&15 in [4,12))
__global__ void prepack_w2(const float* __restrict__ W2, const float* __restrict__ W1,
                           unsigned short* __restrict__ w2b) {
    int idx = blockIdx.x * 256 + threadIdx.x;
    if (idx >= W2B_ELEMS) return;
    int j    = idx & 7;
    int lane = (idx >> 3) & 63;
    int nt   = (idx >> 9) & 7;
    int kidx = idx >> 12;            // 0..17
    int tap  = kidx >> 1;
    int ks   = kidx & 1;
    int ky   = tap / 3;
    int kx   = tap - ky * 3;
    int n    = nt * 16 + (lane & 15);
    int ci   = ks * 32 + (lane >> 4) * 8 + j;
    float v = 0.0f;
    if (n < PPC * CCH) v = W2[((n * HID + ci) * 3 + ky) * 3 + kx];

    // ---- W1 slot? (padding region) ----
    int l15s = lane & 15;
    if (nt == 7 && kidx < 16 && l15s >= 4 && l15s < 12) {
        int f   = kidx >> 1;
        int hi5 = kidx & 1;
        int L   = hi5 * 32 + (lane >> 4) * 8 + (l15s - 4);
        int ks2 = f >> 2;
        int nt1 = f & 3;
        int co  = nt1 * 16 + (L & 15);
        int k   = ks2 * 32 + (L >> 4) * 8 + j;
        v = 0.0f;
        if (k < 36) {
            int tp  = k >> 2;
            int c   = k & 3;
            int ky2 = tp / 3;
            int kx2 = tp - ky2 * 3;
            v = W1[((co * CCH + c) * 3 + ky2) * 3 + kx2];
        }
    }

    unsigned short hi = f2bf(v);
    float rem = v - bf2f(hi);
    w2b[idx]             = hi;
    w2b[idx + W2B_ELEMS] = f2bf(rem);
}

__global__ __launch_bounds__(256, 3)
void fused_kernel(const float* __restrict__ x, const float* __restrict__ clean,
                  const float* __restrict__ b1,
                  const float* __restrict__ b2, const unsigned short* __restrict__ w2b,
                  float* __restrict__ out)
{
    // LDS union (R4): one 29952 B region serves all three phase-local buffers.
    //   [0, 25920)      s_hid   (180*HSTR bf16)   live: Phase B write -> Phase C reads
    //   [25920, 29760)  s_cl    (2*960 bf16)      live: Phase A write -> Phase B reads
    //   [0, 29952)      p_buf   (64*PSTR f32)     live: epilogue only
    // All aliasing is barrier-ordered: s_cl reads end before the post-Phase-C
    // barrier; p_buf stores begin only after that barrier. 30KB static LDS ->
    // 5 workgroups/CU (was 34304 B -> 4).
    __shared__ __align__(16) float s_all[64 * PSTR];       // 29952 B
    __shared__ float s_red[4];

    unsigned short* s_hid = (unsigned short*)s_all;                 // 12960 shorts
    unsigned short* s_cl  = (unsigned short*)s_all + 12960;         // 1920 shorts (8B-aligned)

    const int tid  = threadIdx.x;
    const int blk  = blockIdx.x;
    const int b    = blk >> 9;
    const int ty   = (blk >> 4) & 31;
    const int tx   = blk & 15;
    const int Y0 = ty * TH, X0 = tx * TWD;

    const int w    = tid >> 6;        // wave id == spline channel c
    const int lane = tid & 63;
    const int l15  = lane & 15;
    const int quad = lane >> 4;
    const int wy   = w & 1;           // M half: mtiles wy*4 .. wy*4+3 (pixel rows)
    const int wx   = w >> 1;          // N half: ntiles wx*4 .. wx*4+3

    // ---------- Phase A: stage clean tile (12 x 20 x 4ch, zero-padded) as bf16 hi/lo ----------
    for (int i = tid; i < 960; i += 256) {
        int c  = i / 240;             // plane-major iteration -> coalesced global loads
        int r  = i - c * 240;
        int cy = r / 20;
        int cx = r - cy * 20;
        int iy = Y0 - 2 + cy, ix = X0 - 2 + cx;
        float v = 0.0f;
        if (iy >= 0 && iy < HH && ix >= 0 && ix < WW)
            v = clean[((b*CCH + c) << 16) + iy*WW + ix];
        unsigned short hi = f2bf(v);
        int o = r * 4 + c;            // c-contiguous LDS layout for b64 fragment reads
        s_cl[o]       = hi;
        s_cl[960 + o] = f2bf(v - bf2f(hi));
    }
    __syncthreads();

    // ---------- Phase B: hid = relu(conv1(clean)) via MFMA (implicit GEMM) ----------
    // M = 180 halo pixels (pad 192 -> 12 mtiles, 3/wave), N = 64 (4 ntiles), K = 36 pad 64.
    // Precision: A,B both hi/lo bf16; A_hi*B_hi + A_hi*B_lo + A_lo*B_hi ~= fp32 conv1.
    // Register diet (R3): ah/al hoisted per ks (24 regs), bh/bl loaded one pair
    // at a time (8 regs) -> no 32-reg fragment block live across the MFMA loop.
    {
        const short8v* __restrict__ wv = (const short8v*)w2b;
        const int hi5 = lane >> 5;
        const int mm  = lane & 31;
        const int slotLane = ((mm >> 3) << 4) + 4 + (mm & 7);   // inverse of prepack's L decode

        f32x4 acc1[3][4];
        #pragma unroll
        for (int nt = 0; nt < 4; ++nt) {
            float bv = b1[nt*16 + l15];               // C col = l15 -> co
            #pragma unroll
            for (int mt = 0; mt < 3; ++mt) {
                acc1[mt][nt][0] = bv; acc1[mt][nt][1] = bv;
                acc1[mt][nt][2] = bv; acc1[mt][nt][3] = bv;
            }
        }
        // Per-lane tap offsets: quad q covers taps {2q,2q+1} (ks=0) and tap 8 (ks=1; k>=36 zeroed in B).
        int t0 = quad * 2, t1 = quad * 2 + 1;
        int ky0 = t0 / 3, kx0 = t0 - ky0 * 3;
        int ky1 = t1 / 3, kx1 = t1 - ky1 * 3;
        const int o0 = (ky0 * 20 + kx0) * 4;
        const int o1 = (ky1 * 20 + kx1) * 4;
        const int o8 = (2 * 20 + 2) * 4;              // tap 8 -> (ky,kx)=(2,2)

        #pragma unroll
        for (int ks = 0; ks < 2; ++ks) {
            const int oA = ks ? o8 : o0;
            const int oB = ks ? o8 : o1;
            short8v ah[3], al[3];
            #pragma unroll
            for (int mt = 0; mt < 3; ++mt) {
                int p  = (w*3 + mt)*16 + l15;          // A row = halo pixel
                int pc = p > HALO_PIX-1 ? HALO_PIX-1 : p;   // clamp pad rows (results discarded)
                int hy = pc / 18, hx = pc - hy * 18;
                int base = (hy * 20 + hx) * 4;
                short4v h0 = *(const short4v*)(s_cl + base + oA);
                short4v h1 = *(const short4v*)(s_cl + base + oB);
                short4v g0 = *(const short4v*)(s_cl + 960 + base + oA);
                short4v g1 = *(const short4v*)(s_cl + 960 + base + oB);
                ah[mt] = __builtin_shufflevector(h0, h1, 0,1,2,3,4,5,6,7);
                al[mt] = __builtin_shufflevector(g0, g1, 0,1,2,3,4,5,6,7);
            }
            #pragma unroll
            for (int nt = 0; nt < 4; ++nt) {
                int i8 = (((ks*4 + nt)*2 + hi5)*8 + 7)*64 + slotLane;  // (kidx, nt=7, slotLane)
                short8v bh = wv[i8];
                short8v bl = wv[i8 + 9216];            // + W2B_ELEMS/8 -> lo copy
                #pragma unroll
                for (int mt = 0; mt < 3; ++mt) {
                    acc1[mt][nt] = __builtin_amdgcn_mfma_f32_16x16x32_bf16(ah[mt], bh, acc1[mt][nt], 0,0,0);
                    acc1[mt][nt] = __builtin_amdgcn_mfma_f32_16x16x32_bf16(ah[mt], bl, acc1[mt][nt], 0,0,0);
                    acc1[mt][nt] = __builtin_amdgcn_mfma_f32_16x16x32_bf16(al[mt], bh, acc1[mt][nt], 0,0,0);
                }
            }
        }
        // Write s_hid bf16. Out-of-image halo pixels must be ZERO (conv2 SAME padding), not relu(b1).
        #pragma unroll
        for (int mt = 0; mt < 3; ++mt) {
            #pragma unroll
            for (int r = 0; r < 4; ++r) {
                int p = (w*3 + mt)*16 + quad*4 + r;    // C row = quad*4 + reg
                if (p < HALO_PIX) {
                    int hy = p / 18, hx = p - hy * 18;
                    int iy = Y0 - 1 + hy, ix = X0 - 1 + hx;
                    bool valid = (iy >= 0 && iy < HH && ix >= 0 && ix < WW);
                    #pragma unroll
                    for (int nt = 0; nt < 4; ++nt) {
                        float v = valid ? fmaxf(acc1[mt][nt][r], 0.0f) : 0.0f;
                        s_hid[p*HSTR + nt*16 + l15] = f2bf(v);
                    }
                }
            }
        }
    }
    __syncthreads();

    // ---------- Phase C: conv2 as implicit GEMM via MFMA (B = W2_hi + W2_lo) ----------
    // Wave (wy,wx): 4 mtiles x 4 ntiles = 16 acc tiles (64 f32/thread).
    f32x4 acc[4][4];
    #pragma unroll
    for (int mi = 0; mi < 4; ++mi)
        #pragma unroll
        for (int t = 0; t < 4; ++t) {
            acc[mi][t][0] = 0.f; acc[mi][t][1] = 0.f;
            acc[mi][t][2] = 0.f; acc[mi][t][3] = 0.f;
        }

    const short8v* __restrict__ wbv_hi = (const short8v*)w2b;
    const short8v* __restrict__ wbv_lo = (const short8v*)(w2b + W2B_ELEMS);
    // A addr (shorts): ((wy*4+mi+ky)*18 + l15+kx)*HSTR + quad*8 + ks*32  (16B-aligned -> b128)
    const int abase = (wy*4) * (18*HSTR) + l15*HSTR + quad*8;

    for (int tap = 0; tap < 9; ++tap) {
        int ky = tap / 3;
        int kx = tap - ky * 3;
        int roff = abase + ky*(18*HSTR) + kx*HSTR;
        #pragma unroll
        for (int ks = 0; ks < 2; ++ks) {
            int boff = ((tap*2 + ks)*8 + wx*4)*64 + lane;
            short8v afr[4];
            #pragma unroll
            for (int mi = 0; mi < 4; ++mi)
                afr[mi] = *(const short8v*)(s_hid + roff + mi*(18*HSTR) + ks*32);
            short8v bfr[4];
            #pragma unroll
            for (int t = 0; t < 4; ++t)
                bfr[t] = wbv_hi[boff + t*64];
            // T5: favor this wave while it's in its MFMA cluster (5 blocks/CU at
            // diverse phases -> scheduler has something to arbitrate).
            __builtin_amdgcn_s_setprio(1);
            #pragma unroll
            for (int mi = 0; mi < 4; ++mi)
                #pragma unroll
                for (int t = 0; t < 4; ++t)
                    acc[mi][t] = __builtin_amdgcn_mfma_f32_16x16x32_bf16(
                        afr[mi], bfr[t], acc[mi][t], 0, 0, 0);
            __builtin_amdgcn_s_setprio(0);
            #pragma unroll
            for (int t = 0; t < 4; ++t)
                bfr[t] = wbv_lo[boff + t*64];
            __builtin_amdgcn_s_setprio(1);
            #pragma unroll
            for (int mi = 0; mi < 4; ++mi)
                #pragma unroll
                for (int t = 0; t < 4; ++t)
                    acc[mi][t] = __builtin_amdgcn_mfma_f32_16x16x32_bf16(
                        afr[mi], bfr[t], acc[mi][t], 0, 0, 0);
            __builtin_amdgcn_s_setprio(0);
        }
    }

    // ---------- Epilogue: 2 chunks of 64 pixels through LDS p_buf (aliases s_hid+s_cl), then spline ----------
    // Register diet (R3): no pv[]/chh[]/dv[] arrays; heights selected during the
    // cumsum; only the 2 needed derivatives get softplus (runtime-indexed LDS/b2 reads).
    float* p_buf = s_all;
    const float* b2c = b2 + w * PPC;      // wave-uniform -> scalar loads
    float lad = 0.0f;

    for (int chunk = 0; chunk < 2; ++chunk) {
        __syncthreads();   // chunk 0: all s_hid/s_cl reads done; chunk 1: chunk-0 spline reads done
        if (wy == chunk) {
            #pragma unroll
            for (int mi = 0; mi < 4; ++mi) {
                #pragma unroll
                for (int t = 0; t < 4; ++t) {
                    int col = (wx*4 + t)*16 + l15;
                    if (col < NCOLS) {    // cols >=116 are padding; would wrap PSTR (R3 bug)
                        f32x4 v = acc[mi][t];
                        int base = (mi*16 + quad*4) * PSTR + col;
                        p_buf[base]          = v[0];
                        p_buf[base + PSTR]   = v[1];
                        p_buf[base + 2*PSTR] = v[2];
                        p_buf[base + 3*PSTR] = v[3];
                    }
                }
            }
        }
        __syncthreads();

        // spline: thread -> (c = w, chunk-local pixel = lane)
        int iy = Y0 + chunk*4 + quad;
        int ix = X0 + l15;
        int gidx = ((b*CCH + w) << 16) + iy*WW + ix;
        float xv  = x[gidx];              // issued early; bin search needs it
        float xin = fminf(fmaxf(xv, -TB), TB);

        const int pbase = lane * PSTR + w * PPC;
        const float scale = 0.125f;   // 1/sqrt(HIDDEN)

        // ---- widths softmax -> cw[] ----
        float uw[NB];
        #pragma unroll
        for (int j = 0; j < NB; ++j) uw[j] = (p_buf[pbase + j] + b2c[j]) * scale;
        float mw = uw[0];
        #pragma unroll
        for (int j = 1; j < NB; ++j) mw = fmaxf(mw, uw[j]);
        float sw = 0.0f;
        #pragma unroll
        for (int j = 0; j < NB; ++j) { uw[j] = __expf(uw[j] - mw); sw += uw[j]; }
        float isw = 1.0f / sw;
        float cw[NB+1];
        cw[0] = -TB;
        float run = 0.0f;
        #pragma unroll
        for (int j = 0; j < NB; ++j) {
            float wj = MINW + (1.0f - MINW*NB) * (uw[j] * isw);
            run += wj;
            cw[j+1] = -TB + 2.0f*TB*run;
        }
        cw[NB] = TB;

        // ---- bin search ----
        int cnt = 0;
        #pragma unroll
        for (int k = 0; k <= NB; ++k) cnt += (xin >= cw[k]) ? 1 : 0;
        int idx = cnt - 1;
        idx = idx < 0 ? 0 : (idx > NB-1 ? NB-1 : idx);

        float icw = cw[0], inw = cw[1];
        #pragma unroll
        for (int k = 1; k < NB; ++k) {
            bool m = (idx == k);
            icw = m ? cw[k]   : icw;
            inw = m ? cw[k+1] : inw;
        }

        // ---- heights softmax, ich/inh selected during cumsum (no chh[] array) ----
        float uh[NB];
        #pragma unroll
        for (int j = 0; j < NB; ++j) uh[j] = (p_buf[pbase + NB + j] + b2c[NB + j]) * scale;
        float mh = uh[0];
        #pragma unroll
        for (int j = 1; j < NB; ++j) mh = fmaxf(mh, uh[j]);
        float sh = 0.0f;
        #pragma unroll
        for (int j = 0; j < NB; ++j) { uh[j] = __expf(uh[j] - mh); sh += uh[j]; }
        float ish = 1.0f / sh;
        float ich = -TB, inh = -TB;
        float runh = 0.0f;
        #pragma unroll
        for (int j = 0; j < NB; ++j) {
            float c0 = -TB + 2.0f*TB*runh;            // chh[j]
            float hj = MINH + (1.0f - MINH*NB) * (uh[j] * ish);
            runh += hj;
            float c1 = (j == NB-1) ? TB : (-TB + 2.0f*TB*runh);  // chh[j+1]
            bool m = (idx == j);
            ich = m ? c0 : ich;
            inh = m ? c1 : inh;
        }

        // ---- derivatives: only d0 = dv[idx], d1 = dv[idx+1] (2 softplus, not 9) ----
        // dv[0] = dv[NB] = 1.0 (linear tails); dv[k+1] = MIND + softplus(ud9[k])
        int k0c = idx - 1; k0c = k0c < 0 ? 0 : k0c;
        int k1c = idx > NB-2 ? NB-2 : idx;
        float u0 = p_buf[pbase + 2*NB + k0c] + b2c[2*NB + k0c];
        float u1 = p_buf[pbase + 2*NB + k1c] + b2c[2*NB + k1c];
        float sp0 = fmaxf(u0, 0.0f) + __logf(1.0f + __expf(-fabsf(u0)));
        float sp1 = fmaxf(u1, 0.0f) + __logf(1.0f + __expf(-fabsf(u1)));
        float d0 = (idx == 0)    ? 1.0f : (MIND + sp0);
        float d1 = (idx == NB-1) ? 1.0f : (MIND + sp1);

        float ibw = inw - icw;
        float ihh = inh - ich;
        float idl = ihh / ibw;
        float th  = (xin - icw) / ibw;
        float omt = 1.0f - th;
        float tt  = th * omt;
        float numer = ihh * (idl*th*th + d0*tt);
        float den   = idl + (d0 + d1 - 2.0f*idl)*tt;
        float z_in  = ich + numer/den;
        float dnum  = idl*idl*(d1*th*th + 2.0f*idl*tt + d0*omt*omt);
        float lad_in = __logf(dnum) - 2.0f*__logf(den);
        bool inside = (xv >= -TB) && (xv <= TB);
        float z = inside ? z_in : xv;
        if (inside) lad += lad_in;
        out[gidx] = z;
    }

    // ---------- block-reduce lad, one atomic per block ----------
    #pragma unroll
    for (int off = 32; off >= 1; off >>= 1)
        lad += __shfl_xor(lad, off, 64);
    if (lane == 0) s_red[w] = lad;
    __syncthreads();
    if (tid == 0)
        atomicAdd(out + ZTOT + b, s_red[0] + s_red[1] + s_red[2] + s_red[3]);
}

extern "C" void kernel_launch(void* const* d_in, const int* in_sizes, int n_in,
                              void* d_out, int out_size, void* d_ws, size_t ws_size,
                              hipStream_t stream) {
    const float* x     = (const float*)d_in[0];
    const float* clean = (const float*)d_in[1];
    const float* W1    = (const float*)d_in[2];
    const float* b1    = (const float*)d_in[3];
    const float* W2    = (const float*)d_in[4];
    const float* b2    = (const float*)d_in[5];
    float* out = (float*)d_out;
    unsigned short* w2b = (unsigned short*)d_ws;   // exactly 294912 B (W2 hi+lo, W1 stuffed in padding)

    zero_lad_kernel<<<1, 16, 0, stream>>>(out);
    prepack_w2<<<(W2B_ELEMS + 255)/256, 256, 0, stream>>>(W2, W1, w2b);
    fused_kernel<<<BB*32*16, 256, 0, stream>>>(x, clean, b1, b2, w2b, out);
}

// Round 5
// 356.938 us; speedup vs baseline: 1.3817x; 1.0263x over previous
//
#include <hip/hip_runtime.h>
#include <math.h>

#define NB 10
#define PPC 29          // 3*NB-1
#define CCH 4
#define HID 64
#define HH 256
#define WW 256
#define BB 16
#define TB 1.0f
#define MINW 0.001f
#define MINH 0.001f
#define MIND 0.001f

#define ZTOT (BB*CCH*HH*WW)     // 4194304

// Tile: 16 wide x 8 tall. M=128 pixels, N=128 (116 valid), K=576.
#define TH 8
#define TWD 16
#define HALO_PIX 180            // 10 rows x 18 cols
#define HSTR 72                 // s_hid row stride (bf16): 64 + 8 pad -> rows 16B-aligned (b128 reads)
#define PSTR 117                // p_buf row stride (f32): odd -> conflict-free spline reads
#define NCOLS 116               // valid N columns; >=116 is zero-padding (never stored)
#define W2B_ELEMS (18*8*64*8)   // 73728 bf16 per copy; hi+lo = 294912 B in d_ws (NO extra space used)

typedef __attribute__((ext_vector_type(8))) short short8v;
typedef __attribute__((ext_vector_type(4))) short short4v;
typedef __attribute__((ext_vector_type(4))) float f32x4;

__device__ inline unsigned short f2bf(float f) {
    unsigned u = __float_as_uint(f);
    unsigned r = (u + 0x7FFFu + ((u >> 16) & 1u)) >> 16;
    return (unsigned short)r;
}
__device__ inline float bf2f(unsigned short s) {
    return __uint_as_float(((unsigned)s) << 16);
}

__global__ void zero_lad_kernel(float* out) {
    out[ZTOT + threadIdx.x] = 0.0f;
}

// Prepack W2 -> bf16 fragment order, hi/lo split for ~fp32 effective precision.
// w2b[copy(2)][kidx(18)][ntile(8)][lane(64)][j(8)]
// kidx = tap*2 + ks; n = ntile*16 + (lane&15); ci = ks*32 + (lane>>4)*8 + j
//
// W1 stuffing: W2 columns n>=116 are zero padding whose MFMA products land in
// discarded output cols (epilogue stores only col<116). We stash the conv1
// weight fragments there, so total workspace stays exactly 294912 B:
//   W1 fragment f = ks*4 + nt1 (ks in 0..1, nt1 in 0..3), read-lane L, elem j:
//     co = nt1*16 + (L&15); k = ks*32 + (L>>4)*8 + j; v = (k<36) ? W1[co][k&3][k>>2] : 0
//   stored at (kidx = f*2 + (L>>5), nt = 7, slotLane, j) with
//     m = L&31, slotLane = (m>>3)*16 + 4 + (m&7)   (i.e. lane&15 in [4,12))
__global__ void prepack_w2(const float* __restrict__ W2, const float* __restrict__ W1,
                           unsigned short* __restrict__ w2b) {
    int idx = blockIdx.x * 256 + threadIdx.x;
    if (idx >= W2B_ELEMS) return;
    int j    = idx & 7;
    int lane = (idx >> 3) & 63;
    int nt   = (idx >> 9) & 7;
    int kidx = idx >> 12;            // 0..17
    int tap  = kidx >> 1;
    int ks   = kidx & 1;
    int ky   = tap / 3;
    int kx   = tap - ky * 3;
    int n    = nt * 16 + (lane & 15);
    int ci   = ks * 32 + (lane >> 4) * 8 + j;
    float v = 0.0f;
    if (n < PPC * CCH) v = W2[((n * HID + ci) * 3 + ky) * 3 + kx];

    // ---- W1 slot? (padding region) ----
    int l15s = lane & 15;
    if (nt == 7 && kidx < 16 && l15s >= 4 && l15s < 12) {
        int f   = kidx >> 1;
        int hi5 = kidx & 1;
        int L   = hi5 * 32 + (lane >> 4) * 8 + (l15s - 4);
        int ks2 = f >> 2;
        int nt1 = f & 3;
        int co  = nt1 * 16 + (L & 15);
        int k   = ks2 * 32 + (L >> 4) * 8 + j;
        v = 0.0f;
        if (k < 36) {
            int tp  = k >> 2;
            int c   = k & 3;
            int ky2 = tp / 3;
            int kx2 = tp - ky2 * 3;
            v = W1[((co * CCH + c) * 3 + ky2) * 3 + kx2];
        }
    }

    unsigned short hi = f2bf(v);
    float rem = v - bf2f(hi);
    w2b[idx]             = hi;
    w2b[idx + W2B_ELEMS] = f2bf(rem);
}

__global__ __launch_bounds__(256, 4)
void fused_kernel(const float* __restrict__ x, const float* __restrict__ clean,
                  const float* __restrict__ b1,
                  const float* __restrict__ b2, const unsigned short* __restrict__ w2b,
                  float* __restrict__ out)
{
    // LDS union (R4): one 29952 B region serves all three phase-local buffers.
    //   [0, 25920)      s_hid   (180*HSTR bf16)   live: Phase B write -> Phase C reads
    //   [25920, 29760)  s_cl    (2*960 bf16)      live: Phase A write -> Phase B reads
    //   [0, 29952)      p_buf   (64*PSTR f32)     live: epilogue only
    // All aliasing is barrier-ordered. 30208 B static LDS -> 4 wg/CU at the
    // launch_bounds(256,4) register budget (regs were the binder, not LDS: R4).
    __shared__ __align__(16) float s_all[64 * PSTR];       // 29952 B
    __shared__ float s_red[4];

    unsigned short* s_hid = (unsigned short*)s_all;                 // 12960 shorts
    unsigned short* s_cl  = (unsigned short*)s_all + 12960;         // 1920 shorts (8B-aligned)

    const int tid  = threadIdx.x;
    const int blk  = blockIdx.x;
    const int b    = blk >> 9;
    const int ty   = (blk >> 4) & 31;
    const int tx   = blk & 15;
    const int Y0 = ty * TH, X0 = tx * TWD;

    const int w    = tid >> 6;        // wave id == spline channel c
    const int lane = tid & 63;
    const int l15  = lane & 15;
    const int quad = lane >> 4;
    const int wy   = w & 1;           // M half: mtiles wy*4 .. wy*4+3 (pixel rows)
    const int wx   = w >> 1;          // N half: ntiles wx*4 .. wx*4+3

    // ---------- Phase A: stage clean tile (12 x 20 x 4ch, zero-padded) as bf16 hi/lo ----------
    for (int i = tid; i < 960; i += 256) {
        int c  = i / 240;             // plane-major iteration -> coalesced global loads
        int r  = i - c * 240;
        int cy = r / 20;
        int cx = r - cy * 20;
        int iy = Y0 - 2 + cy, ix = X0 - 2 + cx;
        float v = 0.0f;
        if (iy >= 0 && iy < HH && ix >= 0 && ix < WW)
            v = clean[((b*CCH + c) << 16) + iy*WW + ix];
        unsigned short hi = f2bf(v);
        int o = r * 4 + c;            // c-contiguous LDS layout for b64 fragment reads
        s_cl[o]       = hi;
        s_cl[960 + o] = f2bf(v - bf2f(hi));
    }
    __syncthreads();

    // ---------- Phase B: hid = relu(conv1(clean)) via MFMA (implicit GEMM) ----------
    // M = 180 halo pixels (pad 192 -> 12 mtiles, 3/wave), N = 64 (4 ntiles), K = 36 pad 64.
    // Precision: A,B both hi/lo bf16; A_hi*B_hi + A_hi*B_lo + A_lo*B_hi ~= fp32 conv1.
    {
        const short8v* __restrict__ wv = (const short8v*)w2b;
        const int hi5 = lane >> 5;
        const int mm  = lane & 31;
        const int slotLane = ((mm >> 3) << 4) + 4 + (mm & 7);   // inverse of prepack's L decode

        f32x4 acc1[3][4];
        #pragma unroll
        for (int nt = 0; nt < 4; ++nt) {
            float bv = b1[nt*16 + l15];               // C col = l15 -> co
            #pragma unroll
            for (int mt = 0; mt < 3; ++mt) {
                acc1[mt][nt][0] = bv; acc1[mt][nt][1] = bv;
                acc1[mt][nt][2] = bv; acc1[mt][nt][3] = bv;
            }
        }
        // Per-lane tap offsets: quad q covers taps {2q,2q+1} (ks=0) and tap 8 (ks=1; k>=36 zeroed in B).
        int t0 = quad * 2, t1 = quad * 2 + 1;
        int ky0 = t0 / 3, kx0 = t0 - ky0 * 3;
        int ky1 = t1 / 3, kx1 = t1 - ky1 * 3;
        const int o0 = (ky0 * 20 + kx0) * 4;
        const int o1 = (ky1 * 20 + kx1) * 4;
        const int o8 = (2 * 20 + 2) * 4;              // tap 8 -> (ky,kx)=(2,2)

        #pragma unroll
        for (int ks = 0; ks < 2; ++ks) {
            const int oA = ks ? o8 : o0;
            const int oB = ks ? o8 : o1;
            short8v ah[3], al[3];
            #pragma unroll
            for (int mt = 0; mt < 3; ++mt) {
                int p  = (w*3 + mt)*16 + l15;          // A row = halo pixel
                int pc = p > HALO_PIX-1 ? HALO_PIX-1 : p;   // clamp pad rows (results discarded)
                int hy = pc / 18, hx = pc - hy * 18;
                int base = (hy * 20 + hx) * 4;
                short4v h0 = *(const short4v*)(s_cl + base + oA);
                short4v h1 = *(const short4v*)(s_cl + base + oB);
                short4v g0 = *(const short4v*)(s_cl + 960 + base + oA);
                short4v g1 = *(const short4v*)(s_cl + 960 + base + oB);
                ah[mt] = __builtin_shufflevector(h0, h1, 0,1,2,3,4,5,6,7);
                al[mt] = __builtin_shufflevector(g0, g1, 0,1,2,3,4,5,6,7);
            }
            #pragma unroll
            for (int nt = 0; nt < 4; ++nt) {
                int i8 = (((ks*4 + nt)*2 + hi5)*8 + 7)*64 + slotLane;  // (kidx, nt=7, slotLane)
                short8v bh = wv[i8];
                short8v bl = wv[i8 + 9216];            // + W2B_ELEMS/8 -> lo copy
                #pragma unroll
                for (int mt = 0; mt < 3; ++mt) {
                    acc1[mt][nt] = __builtin_amdgcn_mfma_f32_16x16x32_bf16(ah[mt], bh, acc1[mt][nt], 0,0,0);
                    acc1[mt][nt] = __builtin_amdgcn_mfma_f32_16x16x32_bf16(ah[mt], bl, acc1[mt][nt], 0,0,0);
                    acc1[mt][nt] = __builtin_amdgcn_mfma_f32_16x16x32_bf16(al[mt], bh, acc1[mt][nt], 0,0,0);
                }
            }
        }
        // Write s_hid bf16. Out-of-image halo pixels must be ZERO (conv2 SAME padding), not relu(b1).
        #pragma unroll
        for (int mt = 0; mt < 3; ++mt) {
            #pragma unroll
            for (int r = 0; r < 4; ++r) {
                int p = (w*3 + mt)*16 + quad*4 + r;    // C row = quad*4 + reg
                if (p < HALO_PIX) {
                    int hy = p / 18, hx = p - hy * 18;
                    int iy = Y0 - 1 + hy, ix = X0 - 1 + hx;
                    bool valid = (iy >= 0 && iy < HH && ix >= 0 && ix < WW);
                    #pragma unroll
                    for (int nt = 0; nt < 4; ++nt) {
                        float v = valid ? fmaxf(acc1[mt][nt][r], 0.0f) : 0.0f;
                        s_hid[p*HSTR + nt*16 + l15] = f2bf(v);
                    }
                }
            }
        }
    }
    __syncthreads();

    // ---------- Phase C: conv2 as implicit GEMM via MFMA (B = W2_hi + W2_lo) ----------
    // Wave (wy,wx): 4 mtiles x 4 ntiles = 16 acc tiles (64 f32/thread).
    f32x4 acc[4][4];
    #pragma unroll
    for (int mi = 0; mi < 4; ++mi)
        #pragma unroll
        for (int t = 0; t < 4; ++t) {
            acc[mi][t][0] = 0.f; acc[mi][t][1] = 0.f;
            acc[mi][t][2] = 0.f; acc[mi][t][3] = 0.f;
        }

    const short8v* __restrict__ wbv_hi = (const short8v*)w2b;
    const short8v* __restrict__ wbv_lo = (const short8v*)(w2b + W2B_ELEMS);
    // A addr (shorts): ((wy*4+mi+ky)*18 + l15+kx)*HSTR + quad*8 + ks*32  (16B-aligned -> b128)
    const int abase = (wy*4) * (18*HSTR) + l15*HSTR + quad*8;

    for (int tap = 0; tap < 9; ++tap) {
        int ky = tap / 3;
        int kx = tap - ky * 3;
        int roff = abase + ky*(18*HSTR) + kx*HSTR;
        #pragma unroll
        for (int ks = 0; ks < 2; ++ks) {
            int boff = ((tap*2 + ks)*8 + wx*4)*64 + lane;
            short8v afr[4];
            #pragma unroll
            for (int mi = 0; mi < 4; ++mi)
                afr[mi] = *(const short8v*)(s_hid + roff + mi*(18*HSTR) + ks*32);
            short8v bfr[4];
            #pragma unroll
            for (int t = 0; t < 4; ++t)
                bfr[t] = wbv_hi[boff + t*64];
            __builtin_amdgcn_s_setprio(1);
            #pragma unroll
            for (int mi = 0; mi < 4; ++mi)
                #pragma unroll
                for (int t = 0; t < 4; ++t)
                    acc[mi][t] = __builtin_amdgcn_mfma_f32_16x16x32_bf16(
                        afr[mi], bfr[t], acc[mi][t], 0, 0, 0);
            __builtin_amdgcn_s_setprio(0);
            #pragma unroll
            for (int t = 0; t < 4; ++t)
                bfr[t] = wbv_lo[boff + t*64];
            __builtin_amdgcn_s_setprio(1);
            #pragma unroll
            for (int mi = 0; mi < 4; ++mi)
                #pragma unroll
                for (int t = 0; t < 4; ++t)
                    acc[mi][t] = __builtin_amdgcn_mfma_f32_16x16x32_bf16(
                        afr[mi], bfr[t], acc[mi][t], 0, 0, 0);
            __builtin_amdgcn_s_setprio(0);
        }
    }

    // ---------- Epilogue: 2 chunks of 64 pixels through LDS p_buf (aliases s_hid+s_cl), then spline ----------
    // R5: widths cumsum + bin-search + boundary-select fused into ONE pass
    // (no cw[11] array, no count loop, no select loop) -> ~11 regs + ~50 VALU
    // per chunk saved; bit-identical icw/inw/idx vs the array version.
    float* p_buf = s_all;
    const float* b2c = b2 + w * PPC;      // wave-uniform -> scalar loads
    float lad = 0.0f;

    for (int chunk = 0; chunk < 2; ++chunk) {
        __syncthreads();   // chunk 0: all s_hid/s_cl reads done; chunk 1: chunk-0 spline reads done
        if (wy == chunk) {
            #pragma unroll
            for (int mi = 0; mi < 4; ++mi) {
                #pragma unroll
                for (int t = 0; t < 4; ++t) {
                    int col = (wx*4 + t)*16 + l15;
                    if (col < NCOLS) {    // cols >=116 are padding; would wrap PSTR (R3 bug)
                        f32x4 v = acc[mi][t];
                        int base = (mi*16 + quad*4) * PSTR + col;
                        p_buf[base]          = v[0];
                        p_buf[base + PSTR]   = v[1];
                        p_buf[base + 2*PSTR] = v[2];
                        p_buf[base + 3*PSTR] = v[3];
                    }
                }
            }
        }
        __syncthreads();

        // spline: thread -> (c = w, chunk-local pixel = lane)
        int iy = Y0 + chunk*4 + quad;
        int ix = X0 + l15;
        int gidx = ((b*CCH + w) << 16) + iy*WW + ix;
        float xv  = x[gidx];              // issued early; bin search needs it
        float xin = fminf(fmaxf(xv, -TB), TB);

        const int pbase = lane * PSTR + w * PPC;
        const float scale = 0.125f;   // 1/sqrt(HIDDEN)

        // ---- widths softmax; cumsum fused with bin locate ----
        float uw[NB];
        #pragma unroll
        for (int j = 0; j < NB; ++j) uw[j] = (p_buf[pbase + j] + b2c[j]) * scale;
        float mw = uw[0];
        #pragma unroll
        for (int j = 1; j < NB; ++j) mw = fmaxf(mw, uw[j]);
        float sw = 0.0f;
        #pragma unroll
        for (int j = 0; j < NB; ++j) { uw[j] = __expf(uw[j] - mw); sw += uw[j]; }
        float isw = 1.0f / sw;

        // last j with xin >= cw[j] gives idx (xin >= -TB always -> j=0 triggers)
        float icw = -TB, inw = TB;
        int idx = 0;
        float run = 0.0f;
        float cprev = -TB;
        #pragma unroll
        for (int j = 0; j < NB; ++j) {
            float wj = MINW + (1.0f - MINW*NB) * (uw[j] * isw);
            run += wj;
            float cnext = (j == NB-1) ? TB : (-TB + 2.0f*TB*run);   // cw[j+1]
            bool m = (xin >= cprev);
            icw = m ? cprev : icw;
            inw = m ? cnext : inw;
            idx = m ? j     : idx;
            cprev = cnext;
        }

        // ---- heights softmax, ich/inh selected during cumsum (no chh[] array) ----
        float uh[NB];
        #pragma unroll
        for (int j = 0; j < NB; ++j) uh[j] = (p_buf[pbase + NB + j] + b2c[NB + j]) * scale;
        float mh = uh[0];
        #pragma unroll
        for (int j = 1; j < NB; ++j) mh = fmaxf(mh, uh[j]);
        float sh = 0.0f;
        #pragma unroll
        for (int j = 0; j < NB; ++j) { uh[j] = __expf(uh[j] - mh); sh += uh[j]; }
        float ish = 1.0f / sh;
        float ich = -TB, inh = -TB;
        float runh = 0.0f;
        #pragma unroll
        for (int j = 0; j < NB; ++j) {
            float c0 = -TB + 2.0f*TB*runh;            // chh[j]
            float hj = MINH + (1.0f - MINH*NB) * (uh[j] * ish);
            runh += hj;
            float c1 = (j == NB-1) ? TB : (-TB + 2.0f*TB*runh);  // chh[j+1]
            bool m = (idx == j);
            ich = m ? c0 : ich;
            inh = m ? c1 : inh;
        }

        // ---- derivatives: only d0 = dv[idx], d1 = dv[idx+1] (2 softplus, not 9) ----
        // dv[0] = dv[NB] = 1.0 (linear tails); dv[k+1] = MIND + softplus(ud9[k])
        int k0c = idx - 1; k0c = k0c < 0 ? 0 : k0c;
        int k1c = idx > NB-2 ? NB-2 : idx;
        float u0 = p_buf[pbase + 2*NB + k0c] + b2c[2*NB + k0c];
        float u1 = p_buf[pbase + 2*NB + k1c] + b2c[2*NB + k1c];
        float sp0 = fmaxf(u0, 0.0f) + __logf(1.0f + __expf(-fabsf(u0)));
        float sp1 = fmaxf(u1, 0.0f) + __logf(1.0f + __expf(-fabsf(u1)));
        float d0 = (idx == 0)    ? 1.0f : (MIND + sp0);
        float d1 = (idx == NB-1) ? 1.0f : (MIND + sp1);

        float ibw = inw - icw;
        float ihh = inh - ich;
        float idl = ihh / ibw;
        float th  = (xin - icw) / ibw;
        float omt = 1.0f - th;
        float tt  = th * omt;
        float numer = ihh * (idl*th*th + d0*tt);
        float den   = idl + (d0 + d1 - 2.0f*idl)*tt;
        float z_in  = ich + numer/den;
        float dnum  = idl*idl*(d1*th*th + 2.0f*idl*tt + d0*omt*omt);
        float lad_in = __logf(dnum) - 2.0f*__logf(den);
        bool inside = (xv >= -TB) && (xv <= TB);
        float z = inside ? z_in : xv;
        if (inside) lad += lad_in;
        out[gidx] = z;
    }

    // ---------- block-reduce lad, one atomic per block ----------
    #pragma unroll
    for (int off = 32; off >= 1; off >>= 1)
        lad += __shfl_xor(lad, off, 64);
    if (lane == 0) s_red[w] = lad;
    __syncthreads();
    if (tid == 0)
        atomicAdd(out + ZTOT + b, s_red[0] + s_red[1] + s_red[2] + s_red[3]);
}

extern "C" void kernel_launch(void* const* d_in, const int* in_sizes, int n_in,
                              void* d_out, int out_size, void* d_ws, size_t ws_size,
                              hipStream_t stream) {
    const float* x     = (const float*)d_in[0];
    const float* clean = (const float*)d_in[1];
    const float* W1    = (const float*)d_in[2];
    const float* b1    = (const float*)d_in[3];
    const float* W2    = (const float*)d_in[4];
    const float* b2    = (const float*)d_in[5];
    float* out = (float*)d_out;
    unsigned short* w2b = (unsigned short*)d_ws;   // exactly 294912 B (W2 hi+lo, W1 stuffed in padding)

    zero_lad_kernel<<<1, 16, 0, stream>>>(out);
    prepack_w2<<<(W2B_ELEMS + 255)/256, 256, 0, stream>>>(W2, W1, w2b);
    fused_kernel<<<BB*32*16, 256, 0, stream>>>(x, clean, b1, b2, w2b, out);
}